// Round 9
// baseline (152.439 us; speedup 1.0000x reference)
//
#include <hip/hip_runtime.h>
#include <math.h>

#define Bn 4
#define Cn 64
#define On 64
#define Hn 128
#define Wn 128
#define Kn 9
#define HWn (Hn*Wn)
#define ZROW 16384            // per-batch zero row index
#define XBSTRIDE (16385*64)   // per-batch stride (16384 rows + 1 zero row)

typedef short v8s __attribute__((ext_vector_type(8)));
typedef _Float16 v8h __attribute__((ext_vector_type(8)));
typedef float v4f __attribute__((ext_vector_type(4)));

__device__ inline unsigned short f2bf(float f) {
  unsigned u = __builtin_bit_cast(unsigned, f);
  u += 0x7fff + ((u >> 16) & 1);          // RNE
  return (unsigned short)(u >> 16);
}
__device__ inline float bf2f(unsigned short h) {
  unsigned u = ((unsigned)h) << 16;
  return __builtin_bit_cast(float, u);
}
__device__ inline unsigned short f2h(float f) {
  _Float16 h = (_Float16)f;
  return __builtin_bit_cast(unsigned short, h);
}
__device__ inline float h2f(unsigned v) {
  _Float16 h = __builtin_bit_cast(_Float16, (unsigned short)(v & 0xffff));
  return (float)h;
}

// ---------------------------------------------------------------------------
// K1 prep:
//   blk 0..1023   : x_main  NCHW fp32 -> xT  NHWC bf16 (64-px tiles)
//   blk 1024..2047: x_extra NCHW fp32 -> xeF NHWC f16
//   blk 2048..2111: weight repacks spread over 64 blocks
// ---------------------------------------------------------------------------
__global__ __launch_bounds__(256) void k_prep(
    const float* __restrict__ x_main,
    const float* __restrict__ x_extra,
    const float* __restrict__ weight,
    const float* __restrict__ w_om,
    unsigned short* __restrict__ xT,
    _Float16* __restrict__ xeF,
    unsigned short* __restrict__ Wfrag,
    _Float16* __restrict__ WOMfrag)
{
  const int blk = blockIdx.x;
  const int t = threadIdx.x;
  const int lane = t & 63;
  const int grp = t >> 6;

  if (blk < 2048) {
    __shared__ float tile[64 * 65];
    int isExtra = blk >> 10;
    int b  = (blk >> 8) & 3;
    int p0 = (blk & 255) << 6;
    const float* src = (isExtra ? x_extra : x_main) + b * Cn * HWn + p0;
    #pragma unroll
    for (int i = 0; i < 16; ++i) {
      int c = i * 4 + grp;
      tile[c * 65 + lane] = src[c * HWn + lane];     // 256B coalesced
    }
    __syncthreads();
    if (!isExtra) {
      unsigned short* dst = xT + b * XBSTRIDE + p0 * 64;
      #pragma unroll
      for (int i = 0; i < 16; ++i) {
        int p = i * 4 + grp;
        dst[p * 64 + lane] = f2bf(tile[lane * 65 + p]);   // stride65: no conflict
      }
    } else {
      _Float16* dst = xeF + b * XBSTRIDE + p0 * 64;
      #pragma unroll
      for (int i = 0; i < 16; ++i) {
        int p = i * 4 + grp;
        dst[p * 64 + lane] = (_Float16)tile[lane * 65 + p];
      }
    }
  } else {
    int rb = blk - 2048;   // 0..63
    // main-GEMM weights: A[o=ot*16+(ln&15)][c=hk*32+(ln>>4)*8+j] for (k,ot,hk)
    for (int idx = rb * 256 + t; idx < 36864; idx += 64 * 256) {
      int j  = idx & 7;
      int ln = (idx >> 3) & 63;
      int hk = (idx >> 9) & 1;
      int ot = (idx >> 10) & 3;
      int k  = idx >> 12;
      int o = ot * 16 + (ln & 15);
      int c = hk * 32 + (ln >> 4) * 8 + j;
      Wfrag[idx] = f2bf(weight[(o * Cn + c) * Kn + k]);
    }
    // conv weights: order (k9, half, jt, lane, j); j-rows 27..31 zero
    for (int idx = rb * 256 + t; idx < 18432; idx += 64 * 256) {
      int j    = idx & 7;
      int ln   = (idx >> 3) & 63;
      int jt   = (idx >> 9) & 1;
      int half = (idx >> 10) & 1;
      int k9   = idx >> 11;
      int jo = jt * 16 + (ln & 15);
      int c  = half * 32 + (ln >> 4) * 8 + j;
      float v = (jo < 27) ? w_om[(jo * Cn + c) * Kn + k9] : 0.f;
      WOMfrag[idx] = (_Float16)v;
    }
    if (rb == 0 && t < 256) {
      int b = t >> 6, c = t & 63;
      xT[b * XBSTRIDE + ZROW * 64 + c] = 0;
      xeF[b * XBSTRIDE + ZROW * 64 + c] = (_Float16)0.f;
    }
  }
}

// ---------------------------------------------------------------------------
// K2 fused, barrier-free, sched_barrier-pinned pipeline (round-8 body) +
// XCD-AWARE SWIZZLE: blk&7 selects the XCD (dispatch round-robins blk%8);
// XCD x owns h-slab [x*16, x*16+16) of every batch -> per-XCD L2 working set
// ~2.6MB (fits 4MB) instead of the full ~33MB. Within an XCD, consecutive
// i = blk>>3 are same-batch adjacent-h -> co-resident CU blocks share lines.
// Perf-only heuristic: correctness independent of the mapping.
// ---------------------------------------------------------------------------
__global__ __launch_bounds__(256, 4) void k_fused(
    const unsigned short* __restrict__ xT,
    const _Float16* __restrict__ xeF,
    const unsigned short* __restrict__ Wfrag,
    const _Float16* __restrict__ WOMfrag,
    const float* __restrict__ pre_offset,
    const float* __restrict__ pre_sim,
    const float* __restrict__ b_om,
    const float* __restrict__ bias,
    float* __restrict__ out)
{
  __shared__ float jbuf[4 * 16 * 36];    // per-wave j-values, stride 36
  __shared__ uint4 recbuf[4 * 16 * 9];   // per-wave gather records

  const int t    = threadIdx.x;
  const int lane = t & 63;
  const int wv   = __builtin_amdgcn_readfirstlane(t >> 6);

  // XCD swizzle: blk -> (b, h, w-half)
  const int blk  = blockIdx.x;
  const int xcd  = blk & 7;
  const int i    = blk >> 3;             // 0..127 within XCD
  const int b    = i >> 5;               // 4 batches
  const int hl   = (i >> 1) & 15;        // 16 h's per slab
  const int whalf= i & 1;
  const int h    = xcd * 16 + hl;

  const int wq   = whalf * 4 + wv;       // 16-pixel group (0..7)
  const int kq   = lane >> 4;            // c-subgroup / j-subgroup
  const int n    = lane & 15;            // pixel within tile
  const int w    = wq * 16 + n;

  // ---- Phase 1: offset conv on MFMA
  unsigned tapoff[9];
  #pragma unroll
  for (int k9 = 0; k9 < 9; ++k9) {
    int r  = h - 1 + k9 / 3;
    int cc = w - 1 + k9 % 3;
    bool v = ((unsigned)r < (unsigned)Hn) & ((unsigned)cc < (unsigned)Wn);
    tapoff[k9] = (v ? (unsigned)(r * Wn + cc) : (unsigned)ZROW) * 64u;
  }

  const _Float16* xe = xeF + b * XBSTRIDE;
  const v8h* Wom = (const v8h*)WOMfrag;
  v4f ca0 = {0,0,0,0}, ca1 = {0,0,0,0};
  for (int k9 = 0; k9 < 9; ++k9) {
    #pragma unroll
    for (int half = 0; half < 2; ++half) {
      int abase = ((k9 * 2 + half) * 2) * 64 + lane;
      v8h A0 = Wom[abase];
      v8h A1 = Wom[abase + 64];
      v8h Bt = *(const v8h*)(xe + tapoff[k9] + half * 32 + kq * 8);
      ca0 = __builtin_amdgcn_mfma_f32_16x16x32_f16(A0, Bt, ca0, 0, 0, 0);
      ca1 = __builtin_amdgcn_mfma_f32_16x16x32_f16(A1, Bt, ca1, 0, 0, 0);
    }
  }

  // D: col=lane&15 (pixel), row=kq*4+reg (j). Stride-36 rows: 2-way = free.
  float* jb = jbuf + wv * (16 * 36);
  *(v4f*)(jb + n * 36 + kq * 4)      = ca0;   // j 0..15
  *(v4f*)(jb + n * 36 + 16 + kq * 4) = ca1;   // j 16..31

  // ---- Phase 2: records (same wave reads its own LDS; lgkmcnt ordering only)
  uint4* rb = recbuf + wv * (16 * 9);
  if (kq < 3) {
    #pragma unroll
    for (int kk = 0; kk < 3; ++kk) {
      int k = kq * 3 + kk;
      float sy = jb[n * 36 + 2 * k]     + b_om[2 * k];
      float sx = jb[n * 36 + 2 * k + 1] + b_om[2 * k + 1];
      float sm = jb[n * 36 + 18 + k]    + b_om[18 + k];
      int pbase = ((b * Kn + k) * Hn + h) * Wn + w;
      float2 po = *(const float2*)(pre_offset + pbase * 2);
      float py = 10.f * tanhf(sy) + po.y + (float)(h - 1 + k / 3);
      float px = 10.f * tanhf(sx) + po.x + (float)(w - 1 + k % 3);
      float m  = 1.f / (1.f + expf(-sm * pre_sim[pbase]));
      float fy = floorf(py), fx = floorf(px);
      float dy = py - fy, dx = px - fx;
      int y0 = (int)fy, x0 = (int)fx;
      int y1 = y0 + 1, x1 = x0 + 1;
      bool vy0 = (y0 >= 0) & (y0 < Hn), vy1 = (y1 >= 0) & (y1 < Hn);
      bool vx0 = (x0 >= 0) & (x0 < Wn), vx1 = (x1 >= 0) & (x1 < Wn);
      unsigned r00 = (vy0 & vx0) ? (unsigned)(y0 * Wn + x0) : ZROW;
      unsigned r01 = (vy0 & vx1) ? (unsigned)(y0 * Wn + x1) : ZROW;
      unsigned r10 = (vy1 & vx0) ? (unsigned)(y1 * Wn + x0) : ZROW;
      unsigned r11 = (vy1 & vx1) ? (unsigned)(y1 * Wn + x1) : ZROW;
      float wy0 = 1.f - dy, wx0 = 1.f - dx;
      uint4 rec;
      rec.x = r00 | (r01 << 16);
      rec.y = r10 | (r11 << 16);
      rec.z = (unsigned)f2h(wy0 * wx0 * m) | ((unsigned)f2h(wy0 * dx * m) << 16);
      rec.w = (unsigned)f2h(dy * wx0 * m) | ((unsigned)f2h(dy * dx * m) << 16);
      rb[n * 9 + k] = rec;
    }
  }

  // ---- Phase 3: main GEMM, sched_barrier-pinned pipeline
  v4f acc0 = {0,0,0,0}, acc1 = {0,0,0,0}, acc2 = {0,0,0,0}, acc3 = {0,0,0,0};
  const unsigned short* xb = xT + b * XBSTRIDE;
  const v8s* Wf = (const v8s*)Wfrag;

  // prologue: rec k0 + k1, k0 weights/offsets, k0 half0 corners
  uint4 rec0   = rb[n * 9 + 0];
  uint4 rec_nx = rb[n * 9 + 1];
  float w00 = h2f(rec0.z), w01 = h2f(rec0.z >> 16);
  float w10 = h2f(rec0.w), w11 = h2f(rec0.w >> 16);
  unsigned o00 = (rec0.x & 0xffff) * 64 + kq * 8;
  unsigned o01 = (rec0.x >> 16)    * 64 + kq * 8;
  unsigned o10 = (rec0.y & 0xffff) * 64 + kq * 8;
  unsigned o11 = (rec0.y >> 16)    * 64 + kq * 8;
  v8s C0 = *(const v8s*)(xb + o00);
  v8s C1 = *(const v8s*)(xb + o01);
  v8s C2 = *(const v8s*)(xb + o10);
  v8s C3 = *(const v8s*)(xb + o11);

  #pragma unroll
  for (int k = 0; k < 9; ++k) {
    // ------- load block -------
    v8s H0 = *(const v8s*)(xb + o00 + 32);
    v8s H1 = *(const v8s*)(xb + o01 + 32);
    v8s H2 = *(const v8s*)(xb + o10 + 32);
    v8s H3 = *(const v8s*)(xb + o11 + 32);

    v8s N0, N1, N2, N3;
    float nw00 = 0.f, nw01 = 0.f, nw10 = 0.f, nw11 = 0.f;
    unsigned p00 = 0, p01 = 0, p10 = 0, p11 = 0;
    if (k < 8) {
      nw00 = h2f(rec_nx.z); nw01 = h2f(rec_nx.z >> 16);
      nw10 = h2f(rec_nx.w); nw11 = h2f(rec_nx.w >> 16);
      p00 = (rec_nx.x & 0xffff) * 64 + kq * 8;
      p01 = (rec_nx.x >> 16)    * 64 + kq * 8;
      p10 = (rec_nx.y & 0xffff) * 64 + kq * 8;
      p11 = (rec_nx.y >> 16)    * 64 + kq * 8;
      N0 = *(const v8s*)(xb + p00);
      N1 = *(const v8s*)(xb + p01);
      N2 = *(const v8s*)(xb + p10);
      N3 = *(const v8s*)(xb + p11);
    }
    uint4 rec_nx2 = rec_nx;
    if (k < 7) rec_nx2 = rb[n * 9 + k + 2];

    // ------- pin: loads above, compute below -------
    __builtin_amdgcn_sched_barrier(0);

    const v8s* wk = Wf + (k * 8) * 64 + lane;
    v8s A0 = wk[0 * 64], A1 = wk[1 * 64], A2 = wk[2 * 64], A3 = wk[3 * 64];
    v8s A4 = wk[4 * 64], A5 = wk[5 * 64], A6 = wk[6 * 64], A7 = wk[7 * 64];

    v8s Bf0, Bf1;
    #pragma unroll
    for (int j = 0; j < 8; ++j) {
      float s = fmaf(bf2f((unsigned short)C0[j]), w00,
                fmaf(bf2f((unsigned short)C1[j]), w01,
                fmaf(bf2f((unsigned short)C2[j]), w10,
                     bf2f((unsigned short)C3[j]) * w11)));
      Bf0[j] = (short)f2bf(s);
    }
    #pragma unroll
    for (int j = 0; j < 8; ++j) {
      float s = fmaf(bf2f((unsigned short)H0[j]), w00,
                fmaf(bf2f((unsigned short)H1[j]), w01,
                fmaf(bf2f((unsigned short)H2[j]), w10,
                     bf2f((unsigned short)H3[j]) * w11)));
      Bf1[j] = (short)f2bf(s);
    }

    acc0 = __builtin_amdgcn_mfma_f32_16x16x32_bf16(A0, Bf0, acc0, 0, 0, 0);
    acc1 = __builtin_amdgcn_mfma_f32_16x16x32_bf16(A2, Bf0, acc1, 0, 0, 0);
    acc2 = __builtin_amdgcn_mfma_f32_16x16x32_bf16(A4, Bf0, acc2, 0, 0, 0);
    acc3 = __builtin_amdgcn_mfma_f32_16x16x32_bf16(A6, Bf0, acc3, 0, 0, 0);
    acc0 = __builtin_amdgcn_mfma_f32_16x16x32_bf16(A1, Bf1, acc0, 0, 0, 0);
    acc1 = __builtin_amdgcn_mfma_f32_16x16x32_bf16(A3, Bf1, acc1, 0, 0, 0);
    acc2 = __builtin_amdgcn_mfma_f32_16x16x32_bf16(A5, Bf1, acc2, 0, 0, 0);
    acc3 = __builtin_amdgcn_mfma_f32_16x16x32_bf16(A7, Bf1, acc3, 0, 0, 0);

    if (k < 8) {
      C0 = N0; C1 = N1; C2 = N2; C3 = N3;
      w00 = nw00; w01 = nw01; w10 = nw10; w11 = nw11;
      o00 = p00; o01 = p01; o10 = p10; o11 = p11;
      rec_nx = rec_nx2;
    }
  }

  // epilogue: D col=lane&15 (pix), row=kq*4+reg (o within 16-o tile)
  const float4* b4 = (const float4*)bias;
  float4 vb0 = b4[0 * 4 + kq], vb1 = b4[1 * 4 + kq];
  float4 vb2 = b4[2 * 4 + kq], vb3 = b4[3 * 4 + kq];
  float* ob = out + (b * On) * HWn + h * Wn + wq * 16 + n;
  #pragma unroll
  for (int reg = 0; reg < 4; ++reg) {
    ob[(0 * 16 + kq * 4 + reg) * HWn] = acc0[reg] + ((const float*)&vb0)[reg];
    ob[(1 * 16 + kq * 4 + reg) * HWn] = acc1[reg] + ((const float*)&vb1)[reg];
    ob[(2 * 16 + kq * 4 + reg) * HWn] = acc2[reg] + ((const float*)&vb2)[reg];
    ob[(3 * 16 + kq * 4 + reg) * HWn] = acc3[reg] + ((const float*)&vb3)[reg];
  }
}

extern "C" void kernel_launch(void* const* d_in, const int* in_sizes, int n_in,
                              void* d_out, int out_size, void* d_ws, size_t ws_size,
                              hipStream_t stream) {
  const float* x_main     = (const float*)d_in[0];
  const float* x_extra    = (const float*)d_in[1];
  const float* pre_offset = (const float*)d_in[2];
  const float* pre_sim    = (const float*)d_in[3];
  const float* weight     = (const float*)d_in[4];
  const float* bias       = (const float*)d_in[5];
  const float* w_om       = (const float*)d_in[6];
  const float* b_om       = (const float*)d_in[7];
  float* out = (float*)d_out;

  char* ws = (char*)d_ws;
  unsigned short* xT      = (unsigned short*)(ws);              //  8,389,120 B
  _Float16*       xeF     = (_Float16*)(ws + 8389120);          //  8,389,120 B
  unsigned short* Wfrag   = (unsigned short*)(ws + 16778240);   //     73,728 B
  _Float16*       WOMfrag = (_Float16*)(ws + 16851968);         //     36,864 B

  k_prep<<<2112, 256, 0, stream>>>(x_main, x_extra, weight, w_om,
                                   xT, xeF, Wfrag, WOMfrag);
  k_fused<<<1024, 256, 0, stream>>>(xT, xeF, Wfrag, WOMfrag,
                                    pre_offset, pre_sim, b_om, bias, out);
}